// Round 6
// baseline (712.428 us; speedup 1.0000x reference)
//
#include <hip/hip_runtime.h>

typedef __bf16 bf16_t;
typedef bf16_t bf16x8 __attribute__((ext_vector_type(8)));
typedef float f32x4 __attribute__((ext_vector_type(4)));

#define EPI_STORE 0
#define EPI_GELU 1
#define EPI_RES_WIN 2
#define EPI_RES_ID 3

__device__ __forceinline__ float bf2f(unsigned short u) {
    union { unsigned int i; float f; } x; x.i = ((unsigned int)u) << 16; return x.f;
}
__device__ __forceinline__ unsigned short f2bf(float f) {
    union { __bf16 h; unsigned short u; } c; c.h = (__bf16)f; return c.u;
}
__device__ __forceinline__ float gelu_f(float v) {
    float u = v * (0.7978845608f + 0.0356774081f * v * v);
    return v / (1.0f + __expf(-2.0f * u));
}

// async global->LDS 16B: LDS dest is wave-uniform base + lane*16
__device__ __forceinline__ void async_cp16(const unsigned short* g, unsigned short* l) {
    __builtin_amdgcn_global_load_lds(
        (const __attribute__((address_space(1))) unsigned int*)g,
        (__attribute__((address_space(3))) unsigned int*)l, 16, 0, 0);
}

// window-layout row m (0..32767) -> image-layout row (b*4096 + l)
__device__ __forceinline__ int map_win(int m, int shift) {
    int n = m & 63, w = m >> 6;
    int b = w >> 6, ww = w & 63;
    int hh = ((ww >> 3) * 8 + (n >> 3) + shift) & 63;
    int wc = ((ww & 7) * 8 + (n & 7) + shift) & 63;
    return (b << 12) + (hh << 6) + wc;
}

// ---------------- small kernels ----------------

__global__ void f2bf4_kernel(const float* __restrict__ s0, const float* __restrict__ s1,
                             const float* __restrict__ s2, const float* __restrict__ s3,
                             unsigned short* __restrict__ dst) {
    int i = blockIdx.x * 256 + threadIdx.x;
    const float* s; int off;
    if (i < 884736)       { s = s0; off = 0; }
    else if (i < 1179648) { s = s1; off = 884736; }
    else if (i < 2359296) { s = s2; off = 1179648; }
    else                  { s = s3; off = 2359296; }
    dst[i] = f2bf(s[i - off]);
}

__global__ void silu_kernel(const float* __restrict__ emb,
                            float* __restrict__ out, int n) {
    int i = blockIdx.x * 256 + threadIdx.x;
    if (i < n) { float e = emb[i]; out[i] = e / (1.0f + expf(-e)); }
}

__global__ __launch_bounds__(64) void ada_kernel(
    const float* __restrict__ se,           // [8][384] silu(emb)
    const float* __restrict__ ada_w,        // [2][2304][384]
    const float* __restrict__ ada_b,        // [2][2304]
    float* __restrict__ ada_out)            // [2][8][2304]
{
    int j = blockIdx.x;
    int layer = blockIdx.y;
    int t = threadIdx.x;
    const float* wr = ada_w + ((long)layer * 2304 + j) * 384;
    float w[6];
#pragma unroll
    for (int q = 0; q < 6; q++) w[q] = wr[t + 64 * q];
    float bias = ada_b[layer * 2304 + j];
    for (int b = 0; b < 8; b++) {
        float p = 0.f;
#pragma unroll
        for (int q = 0; q < 6; q++) p += se[b * 384 + t + 64 * q] * w[q];
#pragma unroll
        for (int o = 32; o > 0; o >>= 1) p += __shfl_xor(p, o);
        if (t == 0) ada_out[((long)layer * 8 + b) * 2304 + j] = p + bias;
    }
}

// LayerNorm + adaLN modulate: h = LN(x)*(1+sc) + sh; one wave per row, 4 rows/block
__global__ __launch_bounds__(256) void ln_mod_kernel(
    const float* __restrict__ x, const float* __restrict__ ada,
    unsigned short* __restrict__ h, int sh_off, int sc_off)
{
    int row = blockIdx.x * 4 + (threadIdx.x >> 6);
    int b = row >> 12;
    int t = threadIdx.x & 63;
    const float* xr = x + (long)row * 384;
    float v[6];
    float s = 0.f;
#pragma unroll
    for (int j = 0; j < 6; j++) { v[j] = xr[t + 64 * j]; s += v[j]; }
#pragma unroll
    for (int o = 32; o > 0; o >>= 1) s += __shfl_xor(s, o);
    float mean = s * (1.0f / 384.0f);
    float s2 = 0.f;
#pragma unroll
    for (int j = 0; j < 6; j++) { float d = v[j] - mean; s2 += d * d; }
#pragma unroll
    for (int o = 32; o > 0; o >>= 1) s2 += __shfl_xor(s2, o);
    float rstd = rsqrtf(s2 * (1.0f / 384.0f) + 1e-6f);
    const float* adab = ada + (long)b * 2304;
#pragma unroll
    for (int j = 0; j < 6; j++) {
        int c = t + 64 * j;
        float val = (v[j] - mean) * rstd * (1.0f + adab[sc_off + c]) + adab[sh_off + c];
        h[(long)row * 384 + c] = f2bf(val);
    }
}

// ---------------- GEMM: out[M,N] = A[M,K] @ W[N,K]^T + bias ----------------
// 128x128 tile, BK=32 double-buffered (one barrier/iter), global_load_lds
// width-16 with XOR chunk swizzle, XCD-aware block swizzle, operand-swapped
// MFMA (C^T in regs: lane owns 4 consecutive cols of one row per tile) for
// a register-direct vectorized epilogue.

template <int EPI, bool GATHER, bool RESINIT>
__global__ __launch_bounds__(256, 4) void gemm128(
    const unsigned short* __restrict__ A,
    const unsigned short* __restrict__ W,
    const float* __restrict__ bias,
    unsigned short* __restrict__ out,
    float* __restrict__ xres,
    const float* __restrict__ xbase,
    const float* __restrict__ gvec,
    int M, int N, int K, int shift)
{
    __shared__ __align__(16) unsigned short Sh[16384];  // 32 KiB
    unsigned short* As = Sh;          // 2 bufs x 4096 shorts
    unsigned short* Bs = Sh + 8192;

    const int tid = threadIdx.x;
    const int wv = tid >> 6, lane = tid & 63;

    // XCD swizzle: m-tiles partitioned per XCD, n-tile fastest within an XCD
    const int nx = gridDim.x, ny = gridDim.y;
    const int lin = blockIdx.y * nx + blockIdx.x;
    const int xcd = lin & 7, p = lin >> 3;
    const int m0 = (xcd * (ny >> 3) + p / nx) * 128;
    const int n0 = (p % nx) * 128;

    // staging: lane -> row r4 = lane>>2, chunk c = lane&3 (8 shorts each);
    // fetch global chunk c ^ (r4&3) so LDS slot (row,pc) = global chunk pc^(row&3)
    const int r4 = lane >> 2;
    const int cofs = ((lane & 3) ^ (r4 & 3)) * 8;
    long arow[2], brow[2];
#pragma unroll
    for (int t = 0; t < 2; t++) {
        int rl = wv * 32 + t * 16 + r4;
        arow[t] = GATHER ? (long)map_win(m0 + rl, shift) : (long)(m0 + rl);
        brow[t] = (long)(n0 + rl);
    }

    const int wm = (wv >> 1) * 64, wn = (wv & 1) * 64;
    const int l16 = lane & 15, quad = lane >> 4;
    const int rswz = (quad ^ (l16 & 3)) * 8;   // read chunk offset (shorts)

    f32x4 acc[4][4] = {};
    const int niter = K >> 5;

    // prologue: stage buffer 0
#pragma unroll
    for (int t = 0; t < 2; t++) {
        async_cp16(A + arow[t] * K + cofs, As + (wv * 32 + t * 16) * 32);
        async_cp16(W + brow[t] * K + cofs, Bs + (wv * 32 + t * 16) * 32);
    }

    for (int it = 0; it < niter; it++) {
        __syncthreads();   // drains DMA for buffer it&1
        if (it + 1 < niter) {
            int k0 = (it + 1) << 5;
            int b = (it + 1) & 1;
#pragma unroll
            for (int t = 0; t < 2; t++) {
                async_cp16(A + arow[t] * K + k0 + cofs, As + b * 4096 + (wv * 32 + t * 16) * 32);
                async_cp16(W + brow[t] * K + k0 + cofs, Bs + b * 4096 + (wv * 32 + t * 16) * 32);
            }
        }
        const unsigned short* Ac = As + (it & 1) * 4096;
        const unsigned short* Bc = Bs + (it & 1) * 4096;
        bf16x8 af[4], bfr[4];
#pragma unroll
        for (int i = 0; i < 4; i++)
            af[i] = *(const bf16x8*)&Ac[(wm + i * 16 + l16) * 32 + rswz];
#pragma unroll
        for (int j = 0; j < 4; j++)
            bfr[j] = *(const bf16x8*)&Bc[(wn + j * 16 + l16) * 32 + rswz];
#pragma unroll
        for (int i = 0; i < 4; i++)
#pragma unroll
            for (int j = 0; j < 4; j++)   // swapped operands -> C^T layout
                acc[i][j] = __builtin_amdgcn_mfma_f32_16x16x32_bf16(bfr[j], af[i], acc[i][j], 0, 0, 0);
    }

    // ---- epilogue: lane (l16,quad) owns, per (i,j): row wm+i*16+l16,
    //      cols wn + j*16 + quad*4 .. +3  (acc[i][j][r], r = col offset)
    float4 bv4[4];
#pragma unroll
    for (int j = 0; j < 4; j++)
        bv4[j] = *(const float4*)&bias[n0 + wn + j * 16 + quad * 4];

#pragma unroll
    for (int i = 0; i < 4; i++) {
        int row = m0 + wm + i * 16 + l16;
        if constexpr (EPI == EPI_STORE || EPI == EPI_GELU) {
            unsigned short* orow = out + (long)row * N + n0 + wn + quad * 4;
#pragma unroll
            for (int j = 0; j < 4; j++) {
                float v0 = acc[i][j][0] + bv4[j].x;
                float v1 = acc[i][j][1] + bv4[j].y;
                float v2 = acc[i][j][2] + bv4[j].z;
                float v3 = acc[i][j][3] + bv4[j].w;
                if constexpr (EPI == EPI_GELU) {
                    v0 = gelu_f(v0); v1 = gelu_f(v1); v2 = gelu_f(v2); v3 = gelu_f(v3);
                }
                ushort4 pk = { f2bf(v0), f2bf(v1), f2bf(v2), f2bf(v3) };
                *(ushort4*)&orow[j * 16] = pk;
            }
        } else {
            long dst = (EPI == EPI_RES_WIN) ? (long)map_win(row, shift) : (long)row;
            float* xrow = xres + dst * 384 + n0 + wn + quad * 4;
            const float* grow = gvec + (long)(dst >> 12) * 2304 + n0 + wn + quad * 4;
#pragma unroll
            for (int j = 0; j < 4; j++) {
                float4 gv = *(const float4*)&grow[j * 16];
                float4 xb;
                if constexpr (RESINIT)
                    xb = *(const float4*)&xbase[dst * 384 + n0 + wn + quad * 4 + j * 16];
                else
                    xb = *(const float4*)&xrow[j * 16];
                float4 o;
                o.x = xb.x + gv.x * (acc[i][j][0] + bv4[j].x);
                o.y = xb.y + gv.y * (acc[i][j][1] + bv4[j].y);
                o.z = xb.z + gv.z * (acc[i][j][2] + bv4[j].z);
                o.w = xb.w + gv.w * (acc[i][j][3] + bv4[j].w);
                *(float4*)&xrow[j * 16] = o;
            }
        }
    }
}

// ---------------- MFMA attention: one wave per (window, head), 4 heads/block ----

__device__ __forceinline__ int reg3(int p) { return (p < 56) ? 0 : ((p < 60) ? 1 : 2); }

__global__ __launch_bounds__(256) void attn_kernel(
    const unsigned short* __restrict__ qkv,        // [32768][1152] window layout, bf16
    const float* __restrict__ bias_table,          // layer base [225][12], f32
    unsigned short* __restrict__ out,              // [32768][384] window layout, bf16
    int shift)
{
    __shared__ unsigned short Pl[4][64 * 68];   // P matrix, padded stride 68
    __shared__ unsigned short VTl[4][32 * 68];  // V^T, padded stride 68

    const int wv = threadIdx.x >> 6, lane = threadIdx.x & 63;
    const int head = blockIdx.x * 4 + wv;    // grid.x = 3
    const int win = blockIdx.y;              // 0..511
    const int l16 = lane & 15, quad = lane >> 4;

    unsigned short* P = Pl[wv];
    unsigned short* vt = VTl[wv];

    const long base = (long)win * 64 * 1152 + head * 32;

    bf16x8 qf[4], kf[4];
#pragma unroll
    for (int i = 0; i < 4; i++) {
        qf[i] = *(const bf16x8*)&qkv[base + (long)(i * 16 + l16) * 1152 + quad * 8];
        kf[i] = *(const bf16x8*)&qkv[base + 384 + (long)(i * 16 + l16) * 1152 + quad * 8];
    }
    {
        const uint4* vp = (const uint4*)&qkv[base + 768 + (long)lane * 1152];
#pragma unroll
        for (int c4 = 0; c4 < 4; c4++) {
            uint4 v = vp[c4];
            unsigned int u[4] = {v.x, v.y, v.z, v.w};
#pragma unroll
            for (int e = 0; e < 4; e++) {
                vt[(c4 * 8 + e * 2) * 68 + lane]     = (unsigned short)(u[e] & 0xffffu);
                vt[(c4 * 8 + e * 2 + 1) * 68 + lane] = (unsigned short)(u[e] >> 16);
            }
        }
    }

    // S = Q @ K^T
    f32x4 sacc[4][4] = {};
#pragma unroll
    for (int i = 0; i < 4; i++)
#pragma unroll
        for (int j = 0; j < 4; j++)
            sacc[i][j] = __builtin_amdgcn_mfma_f32_16x16x32_bf16(qf[i], kf[j], sacc[i][j], 0, 0, 0);

    const float scale = 0.17677669529663687f;  // 1/sqrt(32)
    const int ww = win & 63, wi = ww >> 3, wj = ww & 7;

#pragma unroll
    for (int i = 0; i < 4; i++) {
#pragma unroll
        for (int r = 0; r < 4; r++) {
            int n = i * 16 + quad * 4 + r;
            int nr = n >> 3, nc = n & 7;
            int labq = (shift > 0) ? reg3(wi * 8 + nr) * 3 + reg3(wj * 8 + nc) : 0;
            float v[4];
#pragma unroll
            for (int j = 0; j < 4; j++) {
                int m = j * 16 + l16;
                int mr = m >> 3, mc = m & 7;
                float s = sacc[i][j][r] * scale +
                          bias_table[((nr - mr + 7) * 15 + (nc - mc + 7)) * 12 + head];
                if (shift > 0) {
                    int labm = reg3(wi * 8 + mr) * 3 + reg3(wj * 8 + mc);
                    if (labm != labq) s -= 100.0f;
                }
                v[j] = s;
            }
            float mx = fmaxf(fmaxf(v[0], v[1]), fmaxf(v[2], v[3]));
#pragma unroll
            for (int o = 1; o < 16; o <<= 1) mx = fmaxf(mx, __shfl_xor(mx, o));
            float sum = 0.f;
#pragma unroll
            for (int j = 0; j < 4; j++) { v[j] = __expf(v[j] - mx); sum += v[j]; }
#pragma unroll
            for (int o = 1; o < 16; o <<= 1) sum += __shfl_xor(sum, o);
            float inv = 1.0f / sum;
#pragma unroll
            for (int j = 0; j < 4; j++)
                P[n * 68 + j * 16 + l16] = f2bf(v[j] * inv);
        }
    }
    __syncthreads();

    // O = P @ V
    f32x4 oacc[4][2] = {};
#pragma unroll
    for (int kt = 0; kt < 2; kt++) {
        bf16x8 pf[4], vf[2];
#pragma unroll
        for (int i = 0; i < 4; i++)
            pf[i] = *(const bf16x8*)&P[(i * 16 + l16) * 68 + kt * 32 + quad * 8];
#pragma unroll
        for (int jt = 0; jt < 2; jt++)
            vf[jt] = *(const bf16x8*)&vt[(jt * 16 + l16) * 68 + kt * 32 + quad * 8];
#pragma unroll
        for (int i = 0; i < 4; i++)
#pragma unroll
            for (int jt = 0; jt < 2; jt++)
                oacc[i][jt] = __builtin_amdgcn_mfma_f32_16x16x32_bf16(pf[i], vf[jt], oacc[i][jt], 0, 0, 0);
    }

#pragma unroll
    for (int i = 0; i < 4; i++)
#pragma unroll
        for (int jt = 0; jt < 2; jt++)
#pragma unroll
            for (int r = 0; r < 4; r++) {
                int row = i * 16 + quad * 4 + r;
                int col = jt * 16 + l16;
                out[((long)win * 64 + row) * 384 + head * 32 + col] = f2bf(oacc[i][jt][r]);
            }
}

// ---------------- launch ----------------

extern "C" void kernel_launch(void* const* d_in, const int* in_sizes, int n_in,
                              void* d_out, int out_size, void* d_ws, size_t ws_size,
                              hipStream_t stream) {
    const float* x_in   = (const float*)d_in[0];
    const float* emb    = (const float*)d_in[3];
    const float* qkv_w  = (const float*)d_in[4];
    const float* qkv_b  = (const float*)d_in[5];
    const float* proj_w = (const float*)d_in[6];
    const float* proj_b = (const float*)d_in[7];
    const float* ff1_w  = (const float*)d_in[8];
    const float* ff1_b  = (const float*)d_in[9];
    const float* ff2_w  = (const float*)d_in[10];
    const float* ff2_b  = (const float*)d_in[11];
    const float* ada_w  = (const float*)d_in[12];
    const float* ada_b  = (const float*)d_in[13];
    const float* bias_t = (const float*)d_in[14];

    char* ws = (char*)d_ws;
    unsigned short* h_buf   = (unsigned short*)ws;               // 25,165,824
    unsigned short* big_buf = (unsigned short*)(ws + 25165824);  // 100,663,296 (qkv & ff1 share)
    unsigned short* wqkv    = (unsigned short*)(ws + 125829120); // 1,769,472
    unsigned short* wproj   = (unsigned short*)(ws + 127598592); // 589,824
    unsigned short* wff1    = (unsigned short*)(ws + 128188416); // 2,359,296
    unsigned short* wff2    = (unsigned short*)(ws + 130547712); // 2,359,296
    float*          ada_out = (float*)(ws + 132907008);          // 147,456
    float*          se      = (float*)(ws + 133054464);          // 12,288

    float* x_acc = (float*)d_out;  // f32 residual stream lives in d_out

    const int M = 32768;

    f2bf4_kernel<<<13824, 256, 0, stream>>>(qkv_w, proj_w, ff1_w, ff2_w, wqkv);

    silu_kernel<<<(3072 + 255) / 256, 256, 0, stream>>>(emb, se, 3072);
    ada_kernel<<<dim3(2304, 2), 64, 0, stream>>>(se, ada_w, ada_b, ada_out);

    for (int layer = 0; layer < 2; layer++) {
        const int shift = layer ? 4 : 0;
        const float* ada_l = ada_out + (long)layer * 8 * 2304;
        // splits: sh_sa 0, sc_sa 384, g_sa 768, sh_ff 1152, sc_ff 1536, g_ff 1920

        ln_mod_kernel<<<M / 4, 256, 0, stream>>>(layer == 0 ? x_in : x_acc,
                                                 ada_l, h_buf, 0, 384);

        gemm128<EPI_STORE, true, false><<<dim3(9, 256), 256, 0, stream>>>(
            h_buf, wqkv + (long)layer * 1152 * 384, qkv_b + layer * 1152,
            big_buf, nullptr, nullptr, nullptr, M, 1152, 384, shift);

        attn_kernel<<<dim3(3, 512), 256, 0, stream>>>(
            big_buf, bias_t + layer * 225 * 12, h_buf, shift);

        if (layer == 0) {
            gemm128<EPI_RES_WIN, false, true><<<dim3(3, 256), 256, 0, stream>>>(
                h_buf, wproj, proj_b,
                nullptr, x_acc, x_in, ada_l + 768, M, 384, 384, shift);
        } else {
            gemm128<EPI_RES_WIN, false, false><<<dim3(3, 256), 256, 0, stream>>>(
                h_buf, wproj + (long)384 * 384, proj_b + 384,
                nullptr, x_acc, nullptr, ada_l + 768, M, 384, 384, shift);
        }

        ln_mod_kernel<<<M / 4, 256, 0, stream>>>(x_acc, ada_l, h_buf, 1152, 1536);

        gemm128<EPI_GELU, false, false><<<dim3(12, 256), 256, 0, stream>>>(
            h_buf, wff1 + (long)layer * 1536 * 384, ff1_b + layer * 1536,
            big_buf, nullptr, nullptr, nullptr, M, 1536, 384, 0);

        gemm128<EPI_RES_ID, false, false><<<dim3(3, 256), 256, 0, stream>>>(
            big_buf, wff2 + (long)layer * 384 * 1536, ff2_b + layer * 384,
            nullptr, x_acc, nullptr, ada_l + 1920, M, 384, 1536, 0);
    }
}